// Round 5
// baseline (993.987 us; speedup 1.0000x reference)
//
#include <hip/hip_runtime.h>

#define NN 100000
#define RR 8
#define BB 8
#define DD 128
#define EE 800000
#define KT 1152                  // 128 (root) + 8*128 (relations)
#define NBLK 782                 // ceil(NN/128)
#define NSEG2 (NBLK * 1024)      // 800768 padded segment keys
#define AGSTR 136                // bf16 LDS row stride for Aagg (272 B)

typedef __attribute__((ext_vector_type(8))) __bf16 bf16x8;
typedef __attribute__((ext_vector_type(4))) float f32x4;
typedef __attribute__((ext_vector_type(4))) unsigned int u32x4;

__device__ __forceinline__ unsigned short f2bf(float f) {
    unsigned u = __float_as_uint(f);
    u += 0x7fffu + ((u >> 16) & 1u);          // round-to-nearest-even
    return (unsigned short)(u >> 16);
}
__device__ __forceinline__ float bf2f(unsigned short h) {
    return __uint_as_float(((unsigned)h) << 16);
}

// ---------------------------------------------------------------------------
// emb f32 -> bf16 (once; both layers then consume bf16 rows)
// ---------------------------------------------------------------------------
__global__ __launch_bounds__(256) void k_cvt(const float* __restrict__ x,
                                             unsigned short* __restrict__ xh) {
    int i = blockIdx.x * 256 + threadIdx.x;       // over NN*DD/8 = 1,600,000
    f32x4 a = ((const f32x4*)x)[2 * i];
    f32x4 b = ((const f32x4*)x)[2 * i + 1];
    u32x4 o;
    o[0] = (unsigned)f2bf(a[0]) | ((unsigned)f2bf(a[1]) << 16);
    o[1] = (unsigned)f2bf(a[2]) | ((unsigned)f2bf(a[3]) << 16);
    o[2] = (unsigned)f2bf(b[0]) | ((unsigned)f2bf(b[1]) << 16);
    o[3] = (unsigned)f2bf(b[2]) | ((unsigned)f2bf(b[3]) << 16);
    ((u32x4*)xh)[i] = o;
}

// ---------------------------------------------------------------------------
// Counting sort by key = (dst>>7)*1024 + rel*128 + (dst&127)
// ---------------------------------------------------------------------------
__global__ __launch_bounds__(256) void k_cnt(const int* __restrict__ ei,
                                             const int* __restrict__ et,
                                             int* __restrict__ cnt) {
    int e = blockIdx.x * 256 + threadIdx.x;
    if (e < EE) {
        int d = ei[EE + e];
        atomicAdd(&cnt[(d >> 7) * 1024 + et[e] * 128 + (d & 127)], 1);
    }
}

__global__ __launch_bounds__(256) void k_scan_local(const int* __restrict__ cnt,
                                                    int* __restrict__ loc,
                                                    int* __restrict__ bsum) {
    __shared__ int tmp[256];
    int t = threadIdx.x, i = blockIdx.x * 256 + t;
    int v = cnt[i];
    tmp[t] = v; __syncthreads();
    int val = v;
#pragma unroll
    for (int d = 1; d < 256; d <<= 1) {
        int a = (t >= d) ? tmp[t - d] : 0;
        __syncthreads();
        val += a; tmp[t] = val;
        __syncthreads();
    }
    loc[i] = val - v;
    if (t == 255) bsum[blockIdx.x] = val;
}

__global__ void k_scan_bsum(const int* __restrict__ bsum, int* __restrict__ boff) {
    __shared__ int tmp[256];
    const int NB = NSEG2 / 256;             // 3128
    const int CH = 13;                      // 256*13 >= 3128
    int t = threadIdx.x;
    int base = t * CH, s = 0;
    for (int j = 0; j < CH; ++j) { int idx = base + j; if (idx < NB) s += bsum[idx]; }
    tmp[t] = s; __syncthreads();
    int val = s;
#pragma unroll
    for (int d = 1; d < 256; d <<= 1) {
        int a = (t >= d) ? tmp[t - d] : 0;
        __syncthreads();
        val += a; tmp[t] = val;
        __syncthreads();
    }
    int run = val - s;
    for (int j = 0; j < CH; ++j) { int idx = base + j; if (idx < NB) { boff[idx] = run; run += bsum[idx]; } }
}

__global__ __launch_bounds__(256) void k_scan_add(int* __restrict__ loc,
                                                  const int* __restrict__ boff) {
    int i = blockIdx.x * 256 + threadIdx.x;
    loc[i] += boff[i >> 8];
}

// scatter: pack src; uses segoff as its cursor (post-scatter segoff = segment END,
// so k_gemm recovers beg = segoff[key] - cnt[key])
__global__ __launch_bounds__(256) void k_scatter(const int* __restrict__ ei,
                                                 const int* __restrict__ et,
                                                 int* __restrict__ segoff,
                                                 int* __restrict__ spk) {
    int e = blockIdx.x * 256 + threadIdx.x;
    if (e < EE) {
        int d = ei[EE + e];
        int key = (d >> 7) * 1024 + et[e] * 128 + (d & 127);
        int pos = atomicAdd(&segoff[key], 1);
        spk[pos] = ei[e];
    }
}

// ---------------------------------------------------------------------------
// B prep: BT[o][k] bf16 hi/lo; k<128 -> root, else W[r][i][o]
// ---------------------------------------------------------------------------
__global__ __launch_bounds__(256) void k_prepB(const float* __restrict__ root,
                                               const float* __restrict__ comp,
                                               const float* __restrict__ basis,
                                               unsigned short* __restrict__ Bhi,
                                               unsigned short* __restrict__ Blo) {
    int idx = blockIdx.x * 256 + threadIdx.x;   // DD*KT = 147456
    if (idx >= DD * KT) return;
    int o = idx / KT, k = idx - o * KT;
    float v;
    if (k < DD) {
        v = root[k * DD + o];
    } else {
        int r = (k - DD) >> 7, i = (k - DD) & 127;
        float s = 0.f;
#pragma unroll
        for (int b = 0; b < BB; ++b)
            s += comp[r * BB + b] * basis[((size_t)b * DD + i) * DD + o];
        v = s;
    }
    unsigned short hi = f2bf(v);
    Bhi[idx] = hi;
    Blo[idx] = f2bf(v - bf2f(hi));
}

// ---------------------------------------------------------------------------
// Fused agg + GEMM, R5 structure: BARRIER-FREE k-steps.
//  * A-fragments for the root phase and B-fragments for ALL k-steps are
//    loaded DIRECTLY from global (xh rows / Bhi+Blo are L2-resident; the
//    fragment byte layout is identical to what LDS staging produced).
//  * Aggregation runs ONCE per relation: 256 threads = 2 per node, two
//    32-col passes so the live f32 accumulator is 32 regs and DEAD before
//    any MFMA (R2/R3 spill lesson). Result -> Aagg LDS tile, read as
//    A-fragments by the 4 k-steps of that relation.
//  * Barriers: 2 per relation + 1 prologue = 17 total (was 108).
// ---------------------------------------------------------------------------
template <bool WRITE_H1>
__global__ __launch_bounds__(256, 3) void k_gemm(
    const unsigned short* __restrict__ xh,
    const unsigned short* __restrict__ Bhi,
    const unsigned short* __restrict__ Blo,
    const float* __restrict__ bias,
    const int* __restrict__ spk,
    const int* __restrict__ segend,     // post-scatter segoff = segment ends
    const int* __restrict__ cnt,
    unsigned short* __restrict__ h1h,
    float* __restrict__ outf)
{
    __shared__ unsigned short Aagg[128 * AGSTR]; // 34.8 KB
    __shared__ int sbeg[1024];                   // 4 KB
    __shared__ unsigned short scnt_s[1024];      // 2 KB

    const int tid = threadIdx.x;
    const int b = blockIdx.x;
    const int M0 = b * 128;

#pragma unroll
    for (int p = 0; p < 4; ++p) {
        int i = p * 256 + tid;
        int end = segend[b * 1024 + i];
        int c = cnt[b * 1024 + i];
        sbeg[i] = end - c;
        scnt_s[i] = (unsigned short)c;
    }

    const int wave = tid >> 6, lane = tid & 63;
    const int quad = lane >> 4, lm = lane & 15;
    const int node = tid >> 1, half = tid & 1;

    float bv[8];
#pragma unroll
    for (int nt = 0; nt < 8; ++nt) bv[nt] = bias[nt * 16 + lm];

    f32x4 acc[2][8];
#pragma unroll
    for (int a = 0; a < 2; ++a)
#pragma unroll
        for (int n = 0; n < 8; ++n) acc[a][n] = (f32x4){0.f, 0.f, 0.f, 0.f};

    // clamped global row pointers for root-phase a-frags (rows >= NN masked
    // in the epilogue, so duplicated row NN-1 is harmless)
    int r0 = M0 + wave * 32 + lm;      if (r0 > NN - 1) r0 = NN - 1;
    int r1 = M0 + wave * 32 + 16 + lm; if (r1 > NN - 1) r1 = NN - 1;
    const unsigned short* pa0 = xh + (size_t)r0 * DD;
    const unsigned short* pa1 = xh + (size_t)r1 * DD;

    // per-lane B base: row (lm) within each 16-row n-tile, col quad*8
    const unsigned short* pbh = Bhi + (size_t)lm * KT + quad * 8;
    const unsigned short* pbl = Blo + (size_t)lm * KT + quad * 8;

    // one k-step: 16 B-frag global loads (L2) + 32 MFMA. No LDS, no barrier.
    auto mfma_step = [&](bf16x8 af0, bf16x8 af1, int k0) {
#pragma unroll
        for (int nt = 0; nt < 8; ++nt) {
            const size_t ro = (size_t)nt * 16 * KT + k0;
            bf16x8 bh = __builtin_bit_cast(bf16x8, *(const u32x4*)(pbh + ro));
            bf16x8 bl = __builtin_bit_cast(bf16x8, *(const u32x4*)(pbl + ro));
            acc[0][nt] = __builtin_amdgcn_mfma_f32_16x16x32_bf16(af0, bh, acc[0][nt], 0, 0, 0);
            acc[0][nt] = __builtin_amdgcn_mfma_f32_16x16x32_bf16(af0, bl, acc[0][nt], 0, 0, 0);
            acc[1][nt] = __builtin_amdgcn_mfma_f32_16x16x32_bf16(af1, bh, acc[1][nt], 0, 0, 0);
            acc[1][nt] = __builtin_amdgcn_mfma_f32_16x16x32_bf16(af1, bl, acc[1][nt], 0, 0, 0);
        }
    };

    __syncthreads();                     // sbeg/scnt visible to all

    // ---- root phase: 4 k-steps, A direct from global, zero barriers
#pragma unroll
    for (int ks = 0; ks < 4; ++ks) {
        bf16x8 af0 = __builtin_bit_cast(bf16x8, *(const u32x4*)(pa0 + ks * 32 + quad * 8));
        bf16x8 af1 = __builtin_bit_cast(bf16x8, *(const u32x4*)(pa1 + ks * 32 + quad * 8));
        mfma_step(af0, af1, ks * 32);
    }

    // ---- relation phase
    for (int r = 0; r < RR; ++r) {
        const int si = r * 128 + node;
        const int beg = sbeg[si];
        const int cs = (int)scnt_s[si];

        __syncthreads();                 // prev k-steps' Aagg readers done

        // aggregate this (node, rel) segment: 2 passes x 32 cols
#pragma unroll
        for (int p = 0; p < 2; ++p) {
            const int coff = half * 64 + p * 32;
            float vlo[16], vhi[16];
#pragma unroll
            for (int j = 0; j < 16; ++j) { vlo[j] = 0.f; vhi[j] = 0.f; }
            for (int t = 0; t < cs; ++t) {
                const int sp = spk[beg + t];
                const u32x4* ps = (const u32x4*)(xh + (size_t)sp * DD + coff);
                u32x4 c0 = ps[0], c1 = ps[1], c2 = ps[2], c3 = ps[3];
#pragma unroll
                for (int w = 0; w < 4; ++w) {
                    vlo[w]      += __uint_as_float(c0[w] << 16);
                    vhi[w]      += __uint_as_float(c0[w] & 0xFFFF0000u);
                    vlo[4 + w]  += __uint_as_float(c1[w] << 16);
                    vhi[4 + w]  += __uint_as_float(c1[w] & 0xFFFF0000u);
                    vlo[8 + w]  += __uint_as_float(c2[w] << 16);
                    vhi[8 + w]  += __uint_as_float(c2[w] & 0xFFFF0000u);
                    vlo[12 + w] += __uint_as_float(c3[w] << 16);
                    vhi[12 + w] += __uint_as_float(c3[w] & 0xFFFF0000u);
                }
            }
            const float inv = 1.0f / (float)(cs > 1 ? cs : 1);
            unsigned pk[16];
#pragma unroll
            for (int j = 0; j < 16; ++j)
                pk[j] = (unsigned)f2bf(vlo[j] * inv) | ((unsigned)f2bf(vhi[j] * inv) << 16);
            unsigned short* pw = &Aagg[node * AGSTR + coff];
            *(u32x4*)(pw + 0)  = (u32x4){pk[0],  pk[1],  pk[2],  pk[3]};
            *(u32x4*)(pw + 8)  = (u32x4){pk[4],  pk[5],  pk[6],  pk[7]};
            *(u32x4*)(pw + 16) = (u32x4){pk[8],  pk[9],  pk[10], pk[11]};
            *(u32x4*)(pw + 24) = (u32x4){pk[12], pk[13], pk[14], pk[15]};
        }

        __syncthreads();                 // Aagg ready

        // 4 k-steps, A from Aagg LDS, B direct from global — no barriers
#pragma unroll
        for (int s = 0; s < 4; ++s) {
            bf16x8 af0 = __builtin_bit_cast(bf16x8,
                *(const u32x4*)&Aagg[(wave * 32 + lm) * AGSTR + s * 32 + quad * 8]);
            bf16x8 af1 = __builtin_bit_cast(bf16x8,
                *(const u32x4*)&Aagg[(wave * 32 + 16 + lm) * AGSTR + s * 32 + quad * 8]);
            mfma_step(af0, af1, DD + r * 128 + s * 32);
        }
    }

    // ---- epilogue (C/D: col=lane&15, row=quad*4+reg)
#pragma unroll
    for (int mt = 0; mt < 2; ++mt) {
#pragma unroll
        for (int nt = 0; nt < 8; ++nt) {
#pragma unroll
            for (int rg = 0; rg < 4; ++rg) {
                int row = M0 + wave * 32 + mt * 16 + quad * 4 + rg;
                if (row < NN) {
                    int col = nt * 16 + lm;
                    float v = acc[mt][nt][rg] + bv[nt];
                    if (WRITE_H1) h1h[(size_t)row * DD + col] = f2bf(fmaxf(v, 0.f));
                    else          outf[(size_t)row * DD + col] = v;
                }
            }
        }
    }
}

// ---------------------------------------------------------------------------

extern "C" void kernel_launch(void* const* d_in, const int* in_sizes, int n_in,
                              void* d_out, int out_size, void* d_ws, size_t ws_size,
                              hipStream_t stream) {
    const int*   ei     = (const int*)d_in[0];
    const int*   et     = (const int*)d_in[1];
    const float* emb    = (const float*)d_in[2];
    const float* basis1 = (const float*)d_in[3];
    const float* comp1  = (const float*)d_in[4];
    const float* root1  = (const float*)d_in[5];
    const float* bias1  = (const float*)d_in[6];
    const float* basis2 = (const float*)d_in[7];
    const float* comp2  = (const float*)d_in[8];
    const float* root2  = (const float*)d_in[9];
    const float* bias2  = (const float*)d_in[10];
    float* out = (float*)d_out;
    (void)in_sizes; (void)n_in; (void)out_size; (void)ws_size;

    char* ws = (char*)d_ws;
    int*            cnt    = (int*)(ws + 0);           // 3,203,072 B
    int*            segoff = (int*)(ws + 3203072);     // 3,203,072 B (post-scatter = ends)
    int*            spk    = (int*)(ws + 6406144);     // 3,200,000 B
    int*            bsum   = (int*)(ws + 9606144);     // 12,512 B
    int*            boff   = (int*)(ws + 9618656);     // 12,512 B
    unsigned short* Bhi1   = (unsigned short*)(ws + 9656320);    // 294,912 B each
    unsigned short* Blo1   = (unsigned short*)(ws + 9951232);
    unsigned short* Bhi2   = (unsigned short*)(ws + 10246144);
    unsigned short* Blo2   = (unsigned short*)(ws + 10541056);
    unsigned short* embh   = (unsigned short*)(ws + 10835968);   // 25.6 MB
    unsigned short* h1h    = (unsigned short*)(ws + 36435968);   // 25.6 MB -> end 62.0 MB

    hipMemsetAsync(cnt, 0, (size_t)NSEG2 * 4, stream);

    k_cvt       <<<NN * DD / (256 * 8), 256, 0, stream>>>(emb, embh);
    k_cnt       <<<(EE + 255) / 256, 256, 0, stream>>>(ei, et, cnt);
    k_scan_local<<<NSEG2 / 256, 256, 0, stream>>>(cnt, segoff, bsum);
    k_scan_bsum <<<1, 256, 0, stream>>>(bsum, boff);
    k_scan_add  <<<NSEG2 / 256, 256, 0, stream>>>(segoff, boff);
    k_scatter   <<<(EE + 255) / 256, 256, 0, stream>>>(ei, et, segoff, spk);

    k_prepB<<<(DD * KT + 255) / 256, 256, 0, stream>>>(root1, comp1, basis1, Bhi1, Blo1);
    k_prepB<<<(DD * KT + 255) / 256, 256, 0, stream>>>(root2, comp2, basis2, Bhi2, Blo2);

    k_gemm<true> <<<NBLK, 256, 0, stream>>>(embh, Bhi1, Blo1, bias1, spk, segoff, cnt, h1h, nullptr);
    k_gemm<false><<<NBLK, 256, 0, stream>>>(h1h,  Bhi2, Blo2, bias2, spk, segoff, cnt, nullptr, out);
}

// Round 7
// 575.752 us; speedup vs baseline: 1.7264x; 1.7264x over previous
//
#include <hip/hip_runtime.h>

#define NN 100000
#define RR 8
#define BB 8
#define DD 128
#define EE 800000
#define KT 1152                  // 128 (root) + 8*128 (relations)
#define NBLK 782                 // ceil(NN/128)
#define NSEG2 (NBLK * 1024)      // 800768 padded segment keys
#define ASTR 40                  // bf16 LDS row stride for B tiles (80 B)
#define AGSTR 132                // bf16 LDS row stride for Aagg (264 B)

typedef __attribute__((ext_vector_type(8))) __bf16 bf16x8;
typedef __attribute__((ext_vector_type(4))) float f32x4;
typedef __attribute__((ext_vector_type(4))) unsigned int u32x4;

__device__ __forceinline__ unsigned short f2bf(float f) {
    unsigned u = __float_as_uint(f);
    u += 0x7fffu + ((u >> 16) & 1u);          // round-to-nearest-even
    return (unsigned short)(u >> 16);
}
__device__ __forceinline__ float bf2f(unsigned short h) {
    return __uint_as_float(((unsigned)h) << 16);
}

// ---------------------------------------------------------------------------
// emb f32 -> bf16 (once; both layers then consume bf16 rows)
// ---------------------------------------------------------------------------
__global__ __launch_bounds__(256) void k_cvt(const float* __restrict__ x,
                                             unsigned short* __restrict__ xh) {
    int i = blockIdx.x * 256 + threadIdx.x;       // over NN*DD/8 = 1,600,000
    f32x4 a = ((const f32x4*)x)[2 * i];
    f32x4 b = ((const f32x4*)x)[2 * i + 1];
    u32x4 o;
    o[0] = (unsigned)f2bf(a[0]) | ((unsigned)f2bf(a[1]) << 16);
    o[1] = (unsigned)f2bf(a[2]) | ((unsigned)f2bf(a[3]) << 16);
    o[2] = (unsigned)f2bf(b[0]) | ((unsigned)f2bf(b[1]) << 16);
    o[3] = (unsigned)f2bf(b[2]) | ((unsigned)f2bf(b[3]) << 16);
    ((u32x4*)xh)[i] = o;
}

// ---------------------------------------------------------------------------
// Counting sort by key = (dst>>7)*1024 + rel*128 + (dst&127)
// ---------------------------------------------------------------------------
__global__ __launch_bounds__(256) void k_cnt(const int* __restrict__ ei,
                                             const int* __restrict__ et,
                                             int* __restrict__ cnt) {
    int e = blockIdx.x * 256 + threadIdx.x;
    if (e < EE) {
        int d = ei[EE + e];
        atomicAdd(&cnt[(d >> 7) * 1024 + et[e] * 128 + (d & 127)], 1);
    }
}

__global__ __launch_bounds__(256) void k_scan_local(const int* __restrict__ cnt,
                                                    int* __restrict__ loc,
                                                    int* __restrict__ bsum) {
    __shared__ int tmp[256];
    int t = threadIdx.x, i = blockIdx.x * 256 + t;
    int v = cnt[i];
    tmp[t] = v; __syncthreads();
    int val = v;
#pragma unroll
    for (int d = 1; d < 256; d <<= 1) {
        int a = (t >= d) ? tmp[t - d] : 0;
        __syncthreads();
        val += a; tmp[t] = val;
        __syncthreads();
    }
    loc[i] = val - v;
    if (t == 255) bsum[blockIdx.x] = val;
}

__global__ void k_scan_bsum(const int* __restrict__ bsum, int* __restrict__ boff) {
    __shared__ int tmp[256];
    const int NB = NSEG2 / 256;             // 3128
    const int CH = 13;                      // 256*13 >= 3128
    int t = threadIdx.x;
    int base = t * CH, s = 0;
    for (int j = 0; j < CH; ++j) { int idx = base + j; if (idx < NB) s += bsum[idx]; }
    tmp[t] = s; __syncthreads();
    int val = s;
#pragma unroll
    for (int d = 1; d < 256; d <<= 1) {
        int a = (t >= d) ? tmp[t - d] : 0;
        __syncthreads();
        val += a; tmp[t] = val;
        __syncthreads();
    }
    int run = val - s;
    for (int j = 0; j < CH; ++j) { int idx = base + j; if (idx < NB) { boff[idx] = run; run += bsum[idx]; } }
}

__global__ __launch_bounds__(256) void k_scan_add(int* __restrict__ loc,
                                                  const int* __restrict__ boff) {
    int i = blockIdx.x * 256 + threadIdx.x;
    loc[i] += boff[i >> 8];
}

// scatter: pack src; uses segoff as its cursor (post-scatter segoff = segment END,
// so k_gemm recovers beg = segoff[key] - cnt[key])
__global__ __launch_bounds__(256) void k_scatter(const int* __restrict__ ei,
                                                 const int* __restrict__ et,
                                                 int* __restrict__ segoff,
                                                 int* __restrict__ spk) {
    int e = blockIdx.x * 256 + threadIdx.x;
    if (e < EE) {
        int d = ei[EE + e];
        int key = (d >> 7) * 1024 + et[e] * 128 + (d & 127);
        int pos = atomicAdd(&segoff[key], 1);
        spk[pos] = ei[e];
    }
}

// ---------------------------------------------------------------------------
// B prep: BT[o][k] bf16 hi/lo; k<128 -> root, else W[r][i][o]
// ---------------------------------------------------------------------------
__global__ __launch_bounds__(256) void k_prepB(const float* __restrict__ root,
                                               const float* __restrict__ comp,
                                               const float* __restrict__ basis,
                                               unsigned short* __restrict__ Bhi,
                                               unsigned short* __restrict__ Blo) {
    int idx = blockIdx.x * 256 + threadIdx.x;   // DD*KT = 147456
    if (idx >= DD * KT) return;
    int o = idx / KT, k = idx - o * KT;
    float v;
    if (k < DD) {
        v = root[k * DD + o];
    } else {
        int r = (k - DD) >> 7, i = (k - DD) & 127;
        float s = 0.f;
#pragma unroll
        for (int b = 0; b < BB; ++b)
            s += comp[r * BB + b] * basis[((size_t)b * DD + i) * DD + o];
        v = s;
    }
    unsigned short hi = f2bf(v);
    Bhi[idx] = hi;
    Blo[idx] = f2bf(v - bf2f(hi));
}

// ---------------------------------------------------------------------------
// Fused agg + GEMM, R6 structure:
//  * Per-relation aggregation -> Aagg LDS tile (R5, kept: gather once per
//    edge-slice, 32-f32 live accumulator dead before any MFMA).
//  * B tiles staged through LDS with T14 async split (R5's direct-global B
//    was the disaster: 2304B-stride fragment loads on the MFMA path).
//    Invariant at k-step entry: LDS holds tile t, regs (16 VGPR) hold t+1.
//    Per k-step: MFMA(t); barrier; ds_write(t+1); issue loads(t+2); barrier.
//    => every B global load has >= 1 k-step + 2 barriers of slack.
//  * Root-phase A-fragments direct from global (row-local, L2-hot).
//  * LDS 54.3 KB -> 3 blocks/CU. No sbeg/scnt tiles (global loads/relation).
// ---------------------------------------------------------------------------
template <bool WRITE_H1>
__global__ __launch_bounds__(256, 3) void k_gemm(
    const unsigned short* __restrict__ xh,
    const unsigned short* __restrict__ Bhi,
    const unsigned short* __restrict__ Blo,
    const float* __restrict__ bias,
    const int* __restrict__ spk,
    const int* __restrict__ segend,     // post-scatter segoff = segment ends
    const int* __restrict__ cnt,
    unsigned short* __restrict__ h1h,
    float* __restrict__ outf)
{
    __shared__ unsigned short Aagg[128 * AGSTR]; // 33,792 B
    __shared__ unsigned short Bhs[128 * ASTR];   // 10,240 B
    __shared__ unsigned short Bls[128 * ASTR];   // 10,240 B  (total 54,272)

    const int tid = threadIdx.x;
    const int b = blockIdx.x;
    const int M0 = b * 128;

    const int wave = tid >> 6, lane = tid & 63;
    const int quad = lane >> 4, lm = lane & 15;
    const int node = tid >> 1, half = tid & 1;

    f32x4 acc[2][8];
#pragma unroll
    for (int a = 0; a < 2; ++a)
#pragma unroll
        for (int n = 0; n < 8; ++n) acc[a][n] = (f32x4){0.f, 0.f, 0.f, 0.f};

    // ---- B pipeline: regs always hold the NEXT tile (t+1). 16 VGPR.
    const int bro0 = tid >> 2;          // staging row, p=0
    const int bro1 = 64 + (tid >> 2);   // staging row, p=1
    const int bq8 = (tid & 3) * 8;      // 8-short (16 B) column offset
    u32x4 bh0, bh1, bl0, bl1;

    auto bload = [&](int k0) {
        bh0 = *(const u32x4*)(Bhi + (size_t)bro0 * KT + k0 + bq8);
        bl0 = *(const u32x4*)(Blo + (size_t)bro0 * KT + k0 + bq8);
        bh1 = *(const u32x4*)(Bhi + (size_t)bro1 * KT + k0 + bq8);
        bl1 = *(const u32x4*)(Blo + (size_t)bro1 * KT + k0 + bq8);
    };
    auto bwrite = [&]() {
        *(u32x4*)&Bhs[bro0 * ASTR + bq8] = bh0;
        *(u32x4*)&Bls[bro0 * ASTR + bq8] = bl0;
        *(u32x4*)&Bhs[bro1 * ASTR + bq8] = bh1;
        *(u32x4*)&Bls[bro1 * ASTR + bq8] = bl1;
    };

    // one k-step: MFMA on LDS tile t, then rotate pipeline.
    // tail=true: last k-step, no rotation.
    auto kstep = [&](bf16x8 af0, bf16x8 af1, int k0next, bool tail) {
#pragma unroll
        for (int nt = 0; nt < 8; ++nt) {
            bf16x8 bh = __builtin_bit_cast(bf16x8, *(const u32x4*)&Bhs[(nt * 16 + lm) * ASTR + quad * 8]);
            bf16x8 bl = __builtin_bit_cast(bf16x8, *(const u32x4*)&Bls[(nt * 16 + lm) * ASTR + quad * 8]);
            acc[0][nt] = __builtin_amdgcn_mfma_f32_16x16x32_bf16(af0, bh, acc[0][nt], 0, 0, 0);
            acc[0][nt] = __builtin_amdgcn_mfma_f32_16x16x32_bf16(af0, bl, acc[0][nt], 0, 0, 0);
            acc[1][nt] = __builtin_amdgcn_mfma_f32_16x16x32_bf16(af1, bh, acc[1][nt], 0, 0, 0);
            acc[1][nt] = __builtin_amdgcn_mfma_f32_16x16x32_bf16(af1, bl, acc[1][nt], 0, 0, 0);
        }
        if (tail) return;
        __syncthreads();                 // all waves done reading tile t
        bwrite();                        // LDS <- tile t+1
        if (k0next >= 0) bload(k0next);  // regs <- tile t+2 (flies past barrier)
        __syncthreads();                 // tile t+1 visible
    };

    // ---- prologue: fill tile 0 into LDS, tile 1 into regs
    bload(0);
    bwrite();
    bload(32);

    // root-phase A-fragments (direct global, clamped rows; masked in epilogue)
    int r0 = M0 + wave * 32 + lm;      if (r0 > NN - 1) r0 = NN - 1;
    int r1 = M0 + wave * 32 + 16 + lm; if (r1 > NN - 1) r1 = NN - 1;
    const unsigned short* pa0 = xh + (size_t)r0 * DD + quad * 8;
    const unsigned short* pa1 = xh + (size_t)r1 * DD + quad * 8;

    __syncthreads();                     // tile 0 visible

    // ---- root phase: 4 k-steps
#pragma unroll
    for (int ks = 0; ks < 4; ++ks) {
        bf16x8 af0 = __builtin_bit_cast(bf16x8, *(const u32x4*)(pa0 + ks * 32));
        bf16x8 af1 = __builtin_bit_cast(bf16x8, *(const u32x4*)(pa1 + ks * 32));
        const int k0n = (ks < 2) ? (ks + 2) * 32 : DD + (ks - 2) * 32;
        kstep(af0, af1, k0n, false);
    }

    // ---- relation phase
    for (int r = 0; r < RR; ++r) {
        // segment info straight from global (no LDS tile)
        const int gix = b * 1024 + r * 128 + node;
        const int send_ = segend[gix];
        const int cs = cnt[gix];
        const int beg = send_ - cs;

        // aggregate this (node, rel) segment: 2 passes x 32 cols.
        // (prev k-step's trailing barrier already separates these Aagg writes
        //  from relation r-1's MFMA reads)
#pragma unroll
        for (int p = 0; p < 2; ++p) {
            const int coff = half * 64 + p * 32;
            float vlo[16], vhi[16];
#pragma unroll
            for (int j = 0; j < 16; ++j) { vlo[j] = 0.f; vhi[j] = 0.f; }
            for (int t = 0; t < cs; ++t) {
                const int sp = spk[beg + t];
                const u32x4* ps = (const u32x4*)(xh + (size_t)sp * DD + coff);
                u32x4 c0 = ps[0], c1 = ps[1], c2 = ps[2], c3 = ps[3];
#pragma unroll
                for (int w = 0; w < 4; ++w) {
                    vlo[w]      += __uint_as_float(c0[w] << 16);
                    vhi[w]      += __uint_as_float(c0[w] & 0xFFFF0000u);
                    vlo[4 + w]  += __uint_as_float(c1[w] << 16);
                    vhi[4 + w]  += __uint_as_float(c1[w] & 0xFFFF0000u);
                    vlo[8 + w]  += __uint_as_float(c2[w] << 16);
                    vhi[8 + w]  += __uint_as_float(c2[w] & 0xFFFF0000u);
                    vlo[12 + w] += __uint_as_float(c3[w] << 16);
                    vhi[12 + w] += __uint_as_float(c3[w] & 0xFFFF0000u);
                }
            }
            const float inv = 1.0f / (float)(cs > 1 ? cs : 1);
            unsigned pk[16];
#pragma unroll
            for (int j = 0; j < 16; ++j)
                pk[j] = (unsigned)f2bf(vlo[j] * inv) | ((unsigned)f2bf(vhi[j] * inv) << 16);
            unsigned short* pw = &Aagg[node * AGSTR + coff];
            *(u32x4*)(pw + 0)  = (u32x4){pk[0],  pk[1],  pk[2],  pk[3]};
            *(u32x4*)(pw + 8)  = (u32x4){pk[4],  pk[5],  pk[6],  pk[7]};
            *(u32x4*)(pw + 16) = (u32x4){pk[8],  pk[9],  pk[10], pk[11]};
            *(u32x4*)(pw + 24) = (u32x4){pk[12], pk[13], pk[14], pk[15]};
        }

        __syncthreads();                 // Aagg ready (B tile already staged)

        // 4 k-steps, A from Aagg
#pragma unroll
        for (int s = 0; s < 4; ++s) {
            bf16x8 af0 = __builtin_bit_cast(bf16x8,
                *(const u32x4*)&Aagg[(wave * 32 + lm) * AGSTR + s * 32 + quad * 8]);
            bf16x8 af1 = __builtin_bit_cast(bf16x8,
                *(const u32x4*)&Aagg[(wave * 32 + 16 + lm) * AGSTR + s * 32 + quad * 8]);
            const bool tail = (r == RR - 1) && (s == 3);
            const int k0n = (s < 2) ? DD + r * 128 + (s + 2) * 32
                          : ((r < RR - 1) ? DD + (r + 1) * 128 + (s - 2) * 32 : -1);
            kstep(af0, af1, k0n, tail);
        }
    }

    // ---- epilogue (C/D: col=lane&15, row=quad*4+reg)
#pragma unroll
    for (int mt = 0; mt < 2; ++mt) {
#pragma unroll
        for (int nt = 0; nt < 8; ++nt) {
            const float bvn = bias[nt * 16 + lm];
#pragma unroll
            for (int rg = 0; rg < 4; ++rg) {
                int row = M0 + wave * 32 + mt * 16 + quad * 4 + rg;
                if (row < NN) {
                    int col = nt * 16 + lm;
                    float v = acc[mt][nt][rg] + bvn;
                    if (WRITE_H1) h1h[(size_t)row * DD + col] = f2bf(fmaxf(v, 0.f));
                    else          outf[(size_t)row * DD + col] = v;
                }
            }
        }
    }
}

// ---------------------------------------------------------------------------

extern "C" void kernel_launch(void* const* d_in, const int* in_sizes, int n_in,
                              void* d_out, int out_size, void* d_ws, size_t ws_size,
                              hipStream_t stream) {
    const int*   ei     = (const int*)d_in[0];
    const int*   et     = (const int*)d_in[1];
    const float* emb    = (const float*)d_in[2];
    const float* basis1 = (const float*)d_in[3];
    const float* comp1  = (const float*)d_in[4];
    const float* root1  = (const float*)d_in[5];
    const float* bias1  = (const float*)d_in[6];
    const float* basis2 = (const float*)d_in[7];
    const float* comp2  = (const float*)d_in[8];
    const float* root2  = (const float*)d_in[9];
    const float* bias2  = (const float*)d_in[10];
    float* out = (float*)d_out;
    (void)in_sizes; (void)n_in; (void)out_size; (void)ws_size;

    char* ws = (char*)d_ws;
    int*            cnt    = (int*)(ws + 0);           // 3,203,072 B
    int*            segoff = (int*)(ws + 3203072);     // 3,203,072 B (post-scatter = ends)
    int*            spk    = (int*)(ws + 6406144);     // 3,200,000 B
    int*            bsum   = (int*)(ws + 9606144);     // 12,512 B
    int*            boff   = (int*)(ws + 9618656);     // 12,512 B
    unsigned short* Bhi1   = (unsigned short*)(ws + 9656320);    // 294,912 B each
    unsigned short* Blo1   = (unsigned short*)(ws + 9951232);
    unsigned short* Bhi2   = (unsigned short*)(ws + 10246144);
    unsigned short* Blo2   = (unsigned short*)(ws + 10541056);
    unsigned short* embh   = (unsigned short*)(ws + 10835968);   // 25.6 MB
    unsigned short* h1h    = (unsigned short*)(ws + 36435968);   // 25.6 MB -> end 62.0 MB

    hipMemsetAsync(cnt, 0, (size_t)NSEG2 * 4, stream);

    k_cvt       <<<NN * DD / (256 * 8), 256, 0, stream>>>(emb, embh);
    k_cnt       <<<(EE + 255) / 256, 256, 0, stream>>>(ei, et, cnt);
    k_scan_local<<<NSEG2 / 256, 256, 0, stream>>>(cnt, segoff, bsum);
    k_scan_bsum <<<1, 256, 0, stream>>>(bsum, boff);
    k_scan_add  <<<NSEG2 / 256, 256, 0, stream>>>(segoff, boff);
    k_scatter   <<<(EE + 255) / 256, 256, 0, stream>>>(ei, et, segoff, spk);

    k_prepB<<<(DD * KT + 255) / 256, 256, 0, stream>>>(root1, comp1, basis1, Bhi1, Blo1);
    k_prepB<<<(DD * KT + 255) / 256, 256, 0, stream>>>(root2, comp2, basis2, Bhi2, Blo2);

    k_gemm<true> <<<NBLK, 256, 0, stream>>>(embh, Bhi1, Blo1, bias1, spk, segoff, cnt, h1h, nullptr);
    k_gemm<false><<<NBLK, 256, 0, stream>>>(h1h,  Bhi2, Blo2, bias2, spk, segoff, cnt, nullptr, out);
}